// Round 1
// baseline (5213.207 us; speedup 1.0000x reference)
//
#include <hip/hip_runtime.h>
#include <math.h>

// FourRegionAttention on MI355X (gfx950), fp32 throughout.
// B=64, n=2304 (48x48), D=64, heads=8, hd=8.
// Requires ~158 MB of d_ws.

#define SCALE_W  0.3535533905932738f   // 8^-0.5
#define SCALE_RA 0.3535533905932738f
#define LN_EPS 1e-5f

// ---- workspace layout (float offsets) ----
#define OFF_XN   0ull
#define SZ_XN    (64ull*2304*64)            // 9437184
#define OFF_KT   (OFF_XN + SZ_XN)           // k_t [b][h][n][8]
#define SZ_KT    (64ull*8*2304*8)           // 9437184
#define OFF_VT   (OFF_KT + SZ_KT)           // v_t [b][h][n][8]
#define OFF_PG   (OFF_VT + SZ_KT)           // P [b][h][49][49][9]
#define SZ_PG    (512ull*49*49*9)           // 11063808
#define OFF_ECLS (OFF_PG + SZ_PG)           // 512
#define OFF_QC   (OFF_ECLS + 512)           // 64 (scaled q_c)
#define OFF_KC   (OFF_QC + 64)              // 64
#define OFF_VC   (OFF_KC + 64)              // 64
#define OFF_CLOG (OFF_VC + 64)              // 8
#define OFF_BK   (OFF_CLOG + 8)             // 64
#define OFF_BV   (OFF_BK + 64)              // 64
#define OFF_AH   (OFF_BV + 64)              // 512 a_h = Wraq@bqkv_h
#define OFF_W1   (OFF_AH + 512)             // 64  Wraq^T@bk
#define OFF_WZ   (OFF_W1 + 64)              // 64  Wrao@bv
#define OFF_B2   (OFF_WZ + 64)              // 512 Wrak^T@a_h
#define OFF_V2   (OFF_B2 + 512)             // 512 v2_h
#define OFF_UH   (OFF_V2 + 512)             // 512 u_h
#define OFF_CH   (OFF_UH + 512)             // 8   c_h
#define OFF_C1   (OFF_CH + 8)               // 64  const output bias
#define OFF_KQ   (OFF_C1 + 64)              // 4096 Wraq^T@Wrak
#define OFF_WVE  (OFF_KQ + 4096)            // 4096 Wrav@Wwproj
#define OFF_KQP  (OFF_WVE + 4096)           // 4096 KQ@Wwproj
#define OFF_RW   (OFF_KQP + 4096)           // 4096 Wrao@WVE
#define OFF_G    (OFF_RW + 4096)            // 8*4096 G[h][d][e]
#define OFF_Z    (OFF_G + 32768)            // 8*4096 Zt[h][d][e] = Z_h[e][d]

// ---------------- setup kernels ----------------
__global__ void k_setup1(const float* __restrict__ Wqkv, const float* __restrict__ bqkv,
                         const float* __restrict__ cls_tok, const float* __restrict__ Wwqkv,
                         const float* __restrict__ bwqkv, const float* __restrict__ Wwproj,
                         const float* __restrict__ bwproj, const float* __restrict__ Wraq,
                         const float* __restrict__ Wrak, const float* __restrict__ Wrav,
                         const float* __restrict__ Wrao, const float* __restrict__ brao,
                         const float* __restrict__ Wout, const float* __restrict__ bout,
                         float* __restrict__ ws) {
  int tid = threadIdx.x;
  // phase1: cls_qkv (192), bk(64), bv(64), a_h(512)
  for (int idx = tid; idx < 832; idx += 256) {
    if (idx < 192) {
      float s = bwqkv[idx];
      for (int d = 0; d < 64; ++d) s += cls_tok[d] * Wwqkv[idx*64 + d];
      if (idx < 64) ws[OFF_QC + idx] = s * SCALE_W;
      else if (idx < 128) ws[OFF_KC + idx - 64] = s;
      else ws[OFF_VC + idx - 128] = s;
    } else if (idx < 256) {
      int e = idx - 192; float s = 0.f;
      for (int d = 0; d < 64; ++d) s += Wrak[e*64+d] * bwproj[d];
      ws[OFF_BK + e] = s;
    } else if (idx < 320) {
      int e = idx - 256; float s = 0.f;
      for (int d = 0; d < 64; ++d) s += Wrav[e*64+d] * bwproj[d];
      ws[OFF_BV + e] = s;
    } else {
      int t2 = idx - 320; int hh = t2 >> 6, e = t2 & 63; float s = 0.f;
      for (int d = 0; d < 64; ++d) s += Wraq[e*64+d] * bqkv[hh*64+d];
      ws[OFF_AH + t2] = s;
    }
  }
  __syncthreads();
  // phase2: cls_logit(8), w1(64), wz(64), b2(512), ch(8)
  for (int idx = tid; idx < 656; idx += 256) {
    if (idx < 8) {
      float s = 0.f;
      for (int u = 0; u < 8; ++u) s += ws[OFF_QC + idx*8+u] * ws[OFF_KC + idx*8+u];
      ws[OFF_CLOG + idx] = s;
    } else if (idx < 72) {
      int e = idx - 8; float s = 0.f;
      for (int d = 0; d < 64; ++d) s += Wraq[d*64+e] * ws[OFF_BK + d];
      ws[OFF_W1 + e] = s;
    } else if (idx < 136) {
      int e = idx - 72; float s = 0.f;
      for (int d = 0; d < 64; ++d) s += Wrao[e*64+d] * ws[OFF_BV + d];
      ws[OFF_WZ + e] = s;
    } else if (idx < 648) {
      int t2 = idx - 136; int hh = t2 >> 6, e = t2 & 63; float s = 0.f;
      for (int d = 0; d < 64; ++d) s += Wrak[d*64+e] * ws[OFF_AH + hh*64+d];
      ws[OFF_B2 + t2] = s;
    } else {
      int hh = idx - 648; float s = 0.f;
      for (int e = 0; e < 64; ++e) s += ws[OFF_AH + hh*64+e] * ws[OFF_BK + e];
      ws[OFF_CH + hh] = s;
    }
  }
  __syncthreads();
  // phase3: v2(512), uh(512), const1(64)
  for (int idx = tid; idx < 1088; idx += 256) {
    if (idx < 512) {
      int hh = idx >> 6, e = idx & 63; float s = 0.f;
      for (int d = 0; d < 64; ++d) s += Wwproj[d*64+e] * ws[OFF_B2 + hh*64+d];
      ws[OFF_V2 + idx] = s;
    } else if (idx < 1024) {
      int t2 = idx - 512; int hh = t2 >> 6, e = t2 & 63; float s = 0.f;
      for (int d = 0; d < 64; ++d) s += Wqkv[(hh*64+d)*64 + e] * ws[OFF_W1 + d];
      ws[OFF_UH + t2] = s;
    } else {
      int e = idx - 1024; float s = bout[e];
      for (int f = 0; f < 512; ++f)
        s += Wout[e*512+f] * (brao[f & 63] + ws[OFF_WZ + (f & 63)]);
      ws[OFF_C1 + e] = s;
    }
  }
}

__global__ void k_setup2(const float* __restrict__ Wraq, const float* __restrict__ Wrak,
                         const float* __restrict__ Wrav, const float* __restrict__ Wwproj,
                         float* __restrict__ ws) {
  int tid = threadIdx.x; int which = blockIdx.x;
  for (int t = tid; t < 4096; t += 256) {
    int i2 = t >> 6, j2 = t & 63; float s = 0.f;
    if (which == 0) { // KQ[d][e] = sum_f Wraq[f][d]*Wrak[f][e]
      for (int f = 0; f < 64; ++f) s += Wraq[f*64+i2] * Wrak[f*64+j2];
      ws[OFF_KQ + t] = s;
    } else {          // WVE[e][d] = sum_f Wrav[e][f]*Wwproj[f][d]
      for (int f = 0; f < 64; ++f) s += Wrav[i2*64+f] * Wwproj[f*64+j2];
      ws[OFF_WVE + t] = s;
    }
  }
}

__global__ void k_setup3(const float* __restrict__ Wwproj, const float* __restrict__ Wrao,
                         float* __restrict__ ws) {
  int tid = threadIdx.x; int which = blockIdx.x;
  for (int t = tid; t < 4096; t += 256) {
    int i2 = t >> 6, j2 = t & 63; float s = 0.f;
    if (which == 0) { // KQP = KQ @ Wwproj
      for (int f = 0; f < 64; ++f) s += ws[OFF_KQ + i2*64 + f] * Wwproj[f*64 + j2];
      ws[OFF_KQP + t] = s;
    } else {          // RW = Wrao @ WVE
      for (int f = 0; f < 64; ++f) s += Wrao[i2*64 + f] * ws[OFF_WVE + f*64 + j2];
      ws[OFF_RW + t] = s;
    }
  }
}

__global__ void k_setup4(const float* __restrict__ Wqkv, const float* __restrict__ Wout,
                         float* __restrict__ ws) {
  int tid = threadIdx.x; int blk = blockIdx.x;
  if (blk < 8) {       // G[h][d][e] = sum_f Wqkv[(h*64+f)][d] * KQP[f][e]
    int hh = blk;
    for (int t = tid; t < 4096; t += 256) {
      int d2 = t >> 6, e2 = t & 63; float s = 0.f;
      for (int f = 0; f < 64; ++f) s += Wqkv[(hh*64+f)*64 + d2] * ws[OFF_KQP + f*64 + e2];
      ws[OFF_G + hh*4096 + t] = s;
    }
  } else {             // Zt[h][d][e] = Z_h[e][d] = sum_f Wout[e][h*64+f] * RW[f][d]
    int hh = blk - 8;
    for (int t = tid; t < 4096; t += 256) {
      int d2 = t >> 6, e2 = t & 63; float s = 0.f;
      for (int f = 0; f < 64; ++f) s += Wout[e2*512 + hh*64 + f] * ws[OFF_RW + f*64 + d2];
      ws[OFF_Z + hh*4096 + t] = s;
    }
  }
}

// ---------------- LayerNorm + k/v GEMM ----------------
// grid 2304 blocks x 256 threads, 64 tokens/block
__global__ __launch_bounds__(256) void k_lnkv(const float* __restrict__ x,
      const float* __restrict__ ln_g, const float* __restrict__ ln_b,
      const float* __restrict__ Wwqkv, const float* __restrict__ bwqkv,
      float* __restrict__ ws) {
  __shared__ float sm[4352 + 8448 + 128];
  float* xnT = sm;                // [d][68] transposed xn tile
  float* xt  = sm + 4352;         // [tok][65]   (aliased by wkv later)
  float* wkv = sm + 4352;         // [d][132]
  float* muL = sm + 4352 + 8448;  // [64]
  float* rsL = muL + 64;          // [64]

  int tid = threadIdx.x;
  long T0 = (long)blockIdx.x * 64;
  int tok = tid >> 2, seg = tid & 3;

  // load x tile
  const float4* x4 = (const float4*)(x + (T0 + tok)*64 + seg*16);
  float4 va = x4[0], vb = x4[1], vc4 = x4[2], vd = x4[3];
  {
    float* xp = xt + tok*65 + seg*16;
    xp[0]=va.x; xp[1]=va.y; xp[2]=va.z; xp[3]=va.w;
    xp[4]=vb.x; xp[5]=vb.y; xp[6]=vb.z; xp[7]=vb.w;
    xp[8]=vc4.x; xp[9]=vc4.y; xp[10]=vc4.z; xp[11]=vc4.w;
    xp[12]=vd.x; xp[13]=vd.y; xp[14]=vd.z; xp[15]=vd.w;
  }
  __syncthreads();
  if (tid < 64) {
    float s = 0.f;
    for (int i2 = 0; i2 < 64; ++i2) s += xt[tid*65 + i2];
    float mu = s * (1.0f/64.0f);
    float v = 0.f;
    for (int i2 = 0; i2 < 64; ++i2) { float d = xt[tid*65 + i2] - mu; v += d*d; }
    v *= (1.0f/64.0f);
    muL[tid] = mu; rsL[tid] = 1.0f / sqrtf(v + LN_EPS);
  }
  __syncthreads();
  {
    float mu = muL[tok], rs = rsL[tok];
    float xv[16];
    #pragma unroll
    for (int k = 0; k < 16; ++k) {
      int i2 = seg*16 + k;
      float v = (xt[tok*65 + i2] - mu) * rs * ln_g[i2] + ln_b[i2];
      xv[k] = v;
      xnT[i2*68 + tok] = v;
    }
    float4* xng = (float4*)(ws + OFF_XN + (T0 + tok)*64 + seg*16);
    xng[0] = make_float4(xv[0], xv[1], xv[2], xv[3]);
    xng[1] = make_float4(xv[4], xv[5], xv[6], xv[7]);
    xng[2] = make_float4(xv[8], xv[9], xv[10], xv[11]);
    xng[3] = make_float4(xv[12], xv[13], xv[14], xv[15]);
  }
  __syncthreads();  // xt dead; load weights into union region
  {
    int o = tid >> 1, dh = (tid & 1) * 32;
    #pragma unroll
    for (int k = 0; k < 32; k += 4) {
      float4 w4 = *(const float4*)(Wwqkv + (64 + o)*64 + dh + k);
      wkv[(dh+k+0)*132 + o] = w4.x;
      wkv[(dh+k+1)*132 + o] = w4.y;
      wkv[(dh+k+2)*132 + o] = w4.z;
      wkv[(dh+k+3)*132 + o] = w4.w;
    }
  }
  __syncthreads();
  // GEMM: 64 tok x 128 out
  int tokq = tid & 15, og = tid >> 4;
  float acc[4][8];
  #pragma unroll
  for (int ti = 0; ti < 4; ++ti)
    #pragma unroll
    for (int k = 0; k < 8; ++k) acc[ti][k] = 0.f;
  for (int d2 = 0; d2 < 64; ++d2) {
    float4 a4 = *(float4*)&xnT[d2*68 + tokq*4];
    float4 b0 = *(float4*)&wkv[d2*132 + og*8];
    float4 b1 = *(float4*)&wkv[d2*132 + og*8 + 4];
    float aa[4] = {a4.x, a4.y, a4.z, a4.w};
    float bbv[8] = {b0.x,b0.y,b0.z,b0.w,b1.x,b1.y,b1.z,b1.w};
    #pragma unroll
    for (int ti = 0; ti < 4; ++ti)
      #pragma unroll
      for (int k = 0; k < 8; ++k) acc[ti][k] += aa[ti]*bbv[k];
  }
  int hh2 = og & 7;
  float bsv[8];
  #pragma unroll
  for (int k = 0; k < 8; ++k) bsv[k] = bwqkv[64 + og*8 + k];
  unsigned long long dstoff = (og < 8) ? OFF_KT : OFF_VT;
  #pragma unroll
  for (int ti = 0; ti < 4; ++ti) {
    long ntok = T0 + tokq*4 + ti;
    int bb = (int)(ntok / 2304);
    int nl = (int)(ntok % 2304);
    float* dst = ws + dstoff + ((long)(bb*8 + hh2)*2304 + nl)*8;
    *(float4*)dst = make_float4(acc[ti][0]+bsv[0], acc[ti][1]+bsv[1], acc[ti][2]+bsv[2], acc[ti][3]+bsv[3]);
    *(float4*)(dst+4) = make_float4(acc[ti][4]+bsv[4], acc[ti][5]+bsv[5], acc[ti][6]+bsv[6], acc[ti][7]+bsv[7]);
  }
}

// ---------------- logits + softmax-normalizer + 2D prefix sums ----------------
// grid 1024: blk = (bh<<1)|g ; g selects channel half. 256 threads.
__global__ __launch_bounds__(256) void k_prefix(float* __restrict__ ws) {
  __shared__ float lg[2304];
  __shared__ float Pp[49*49*5];
  __shared__ float red[256];
  int tid = threadIdx.x;
  int blk = blockIdx.x;
  int g = blk & 1, bh = blk >> 1;
  int hh = bh & 7;
  const float* kt = ws + OFF_KT + (long)bh*2304*8;
  const float* vt = ws + OFF_VT + (long)bh*2304*8 + (g ? 4 : 0);
  float qc[8];
  #pragma unroll
  for (int u = 0; u < 8; ++u) qc[u] = ws[OFF_QC + hh*8 + u];
  float mloc = -1e30f;
  #pragma unroll
  for (int it = 0; it < 9; ++it) {
    int nn = tid + it*256;
    const float4* kk = (const float4*)(kt + nn*8);
    float4 k0 = kk[0], k1 = kk[1];
    float lv = qc[0]*k0.x + qc[1]*k0.y + qc[2]*k0.z + qc[3]*k0.w
             + qc[4]*k1.x + qc[5]*k1.y + qc[6]*k1.z + qc[7]*k1.w;
    lg[nn] = lv;
    mloc = fmaxf(mloc, lv);
  }
  red[tid] = mloc;
  __syncthreads();
  for (int s2 = 128; s2 > 0; s2 >>= 1) {
    if (tid < s2) red[tid] = fmaxf(red[tid], red[tid + s2]);
    __syncthreads();
  }
  float m = fmaxf(red[0], ws[OFF_CLOG + hh]);
  if (tid == 0 && g == 0) ws[OFF_ECLS + bh] = expf(ws[OFF_CLOG + hh] - m);
  #pragma unroll
  for (int it = 0; it < 9; ++it) {
    int nn = tid + it*256;
    lg[nn] = expf(lg[nn] - m);
  }
  // zero P
  for (int idx = tid; idx < 49*49*5; idx += 256) Pp[idx] = 0.f;
  __syncthreads();
  int nc = g ? 4 : 5;
  #pragma unroll
  for (int it = 0; it < 9; ++it) {
    int nn = tid + it*256;
    int i2 = nn / 48, j2 = nn % 48;
    float ev = lg[nn];
    float4 v4 = *(const float4*)(vt + nn*8);
    float* cell = &Pp[((i2+1)*49 + (j2+1))*5];
    if (g == 0) {
      cell[0] = ev; cell[1] = ev*v4.x; cell[2] = ev*v4.y; cell[3] = ev*v4.z; cell[4] = ev*v4.w;
    } else {
      cell[0] = ev*v4.x; cell[1] = ev*v4.y; cell[2] = ev*v4.z; cell[3] = ev*v4.w;
    }
  }
  __syncthreads();
  // vertical cumsum (axis i) -- matches reference axis=2-first order
  for (int idx = tid; idx < 48*nc; idx += 256) {
    int j2 = idx / nc + 1, c = idx % nc;
    for (int i2 = 2; i2 <= 48; ++i2)
      Pp[(i2*49 + j2)*5 + c] += Pp[((i2-1)*49 + j2)*5 + c];
  }
  __syncthreads();
  // horizontal cumsum (axis j)
  for (int idx = tid; idx < 48*nc; idx += 256) {
    int i2 = idx / nc + 1, c = idx % nc;
    for (int j2 = 2; j2 <= 48; ++j2)
      Pp[(i2*49 + j2)*5 + c] += Pp[(i2*49 + j2 - 1)*5 + c];
  }
  __syncthreads();
  // write out P [49][49][9]
  float* pg = ws + OFF_PG + (long)bh*21609;
  int tot = 2401 * nc;
  for (int idx = tid; idx < tot; idx += 256) {
    int cell2 = idx / nc, c = idx % nc;
    pg[cell2*9 + (g ? 5 + c : c)] = Pp[cell2*5 + c];
  }
}

// ---------------- main fused kernel ----------------
// grid 4608 blocks x 256 threads, 32 tokens/block.
__global__ __launch_bounds__(256, 2) void k_main(float* __restrict__ ws,
                                                 float* __restrict__ outp) {
  __shared__ float clsL[4*64*33];   // [r][e][tok(33)]
  __shared__ float gL[64*68];       // [d][68]: cols 0..63 = G/Z, col 64 = u
  __shared__ float tC[64*33];       // cbar [d][tok]
  __shared__ float part[4*8*33];    // [r][eg][tok]
  __shared__ float attnL[4*32];
  __shared__ float s0L[32];

  int tid = threadIdx.x;
  int tok = tid & 31, eg = tid >> 5;
  long T0 = (long)blockIdx.x * 32;
  int b = (int)(T0 / 2304);
  int n = (int)(T0 % 2304) + tok;
  int i2 = n / 48, j2 = n % 48;

  // xn into registers
  float xr[64];
  {
    const float4* p4 = (const float4*)(ws + OFF_XN + (T0 + tok)*64);
    #pragma unroll
    for (int w = 0; w < 16; ++w) {
      float4 t4 = p4[w];
      xr[4*w+0]=t4.x; xr[4*w+1]=t4.y; xr[4*w+2]=t4.z; xr[4*w+3]=t4.w;
    }
  }
  float co[8];
  #pragma unroll
  for (int k = 0; k < 8; ++k) co[k] = ws[OFF_C1 + eg*8 + k];
  float oacc[8];
  #pragma unroll
  for (int k = 0; k < 8; ++k) oacc[k] = 0.f;

  // phase0: build cls_out tile from prefix sums; thread = (tok, head=eg)
  {
    int hh = eg;
    float ec = ws[OFF_ECLS + b*8 + hh];
    const float* P = ws + OFF_PG + ((long)(b*8 + hh))*21609;
    int p_ij  = (i2*49 + j2)*9;
    int p_ij1 = p_ij + 9;
    int p_iW  = (i2*49 + 48)*9;
    int p_1j  = ((i2+1)*49 + j2)*9;
    int p_1j1 = p_1j + 9;
    int p_1W  = ((i2+1)*49 + 48)*9;
    int p_Hj  = (48*49 + j2)*9;
    int p_Hj1 = p_Hj + 9;
    int p_HW  = (48*49 + 48)*9;
    float rden[4];
    {
      float tl = P[p_1j1];
      float tr = P[p_1W] - P[p_1j];
      float bl = P[p_Hj1] - P[p_ij1];
      float br = P[p_HW] - P[p_iW] - P[p_Hj] + P[p_ij];
      rden[0] = 1.0f/(ec + tl); rden[1] = 1.0f/(ec + tr);
      rden[2] = 1.0f/(ec + bl); rden[3] = 1.0f/(ec + br);
    }
    #pragma unroll
    for (int u = 0; u < 8; ++u) {
      int c = 1 + u;
      float tl = P[p_1j1 + c];
      float tr = P[p_1W + c] - P[p_1j + c];
      float bl = P[p_Hj1 + c] - P[p_ij1 + c];
      float br = P[p_HW + c] - P[p_iW + c] - P[p_Hj + c] + P[p_ij + c];
      float nv = ec * ws[OFF_VC + hh*8 + u];
      int e = hh*8 + u;
      clsL[(0*64 + e)*33 + tok] = (nv + tl) * rden[0];
      clsL[(1*64 + e)*33 + tok] = (nv + tr) * rden[1];
      clsL[(2*64 + e)*33 + tok] = (nv + bl) * rden[2];
      clsL[(3*64 + e)*33 + tok] = (nv + br) * rden[3];
    }
  }
  __syncthreads();

  for (int hh = 0; hh < 8; ++hh) {
    // load G_h (+u_h col 64) into gL
    {
      const float4* src = (const float4*)(ws + OFF_G + hh*4096 + tid*16);
      int d2 = tid >> 2, e0 = (tid & 3)*16;
      #pragma unroll
      for (int k = 0; k < 4; ++k) {
        float4 t4 = src[k];
        *(float4*)&gL[d2*68 + e0 + k*4] = t4;
      }
      if (tid < 64) gL[tid*68 + 64] = ws[OFF_UH + hh*64 + tid];
    }
    __syncthreads();
    // stage1: t_h = G_h^T xn (+v2), s0 = xn.u + c
    float acc[8];
    #pragma unroll
    for (int k = 0; k < 8; ++k) acc[k] = ws[OFF_V2 + hh*64 + eg*8 + k];
    float as0 = 0.f;
    #pragma unroll
    for (int d2 = 0; d2 < 64; ++d2) {
      float xv = xr[d2];
      float4 g0 = *(float4*)&gL[d2*68 + eg*8];
      float4 g1 = *(float4*)&gL[d2*68 + eg*8 + 4];
      acc[0] += xv*g0.x; acc[1] += xv*g0.y; acc[2] += xv*g0.z; acc[3] += xv*g0.w;
      acc[4] += xv*g1.x; acc[5] += xv*g1.y; acc[6] += xv*g1.z; acc[7] += xv*g1.w;
      if (eg == 0) as0 += xv * gL[d2*68 + 64];
    }
    if (eg == 0) s0L[tok] = as0 + ws[OFF_CH + hh];
    // stage2: score partials (from registers)
    #pragma unroll
    for (int r = 0; r < 4; ++r) {
      float p = 0.f;
      #pragma unroll
      for (int k = 0; k < 8; ++k) p += acc[k] * clsL[(r*64 + eg*8 + k)*33 + tok];
      part[(r*8 + eg)*33 + tok] = p;
    }
    __syncthreads();
    // softmax over 4 regions
    if (tid < 32) {
      float sc[4];
      #pragma unroll
      for (int r = 0; r < 4; ++r) {
        float s = s0L[tid];
        #pragma unroll
        for (int e2 = 0; e2 < 8; ++e2) s += part[(r*8 + e2)*33 + tid];
        sc[r] = s * SCALE_RA;
      }
      float mm = fmaxf(fmaxf(sc[0], sc[1]), fmaxf(sc[2], sc[3]));
      float ex0 = expf(sc[0]-mm), ex1 = expf(sc[1]-mm), ex2 = expf(sc[2]-mm), ex3 = expf(sc[3]-mm);
      float inv = 1.0f/(ex0+ex1+ex2+ex3);
      attnL[0*32+tid] = ex0*inv; attnL[1*32+tid] = ex1*inv;
      attnL[2*32+tid] = ex2*inv; attnL[3*32+tid] = ex3*inv;
    }
    __syncthreads();
    // cbar into tC, and load Z_h into gL
    {
      float av0 = attnL[0*32+tok], av1 = attnL[1*32+tok];
      float av2 = attnL[2*32+tok], av3 = attnL[3*32+tok];
      #pragma unroll
      for (int k = 0; k < 8; ++k) {
        int d2 = eg*8 + k;
        float c = av0*clsL[(0*64+d2)*33+tok] + av1*clsL[(1*64+d2)*33+tok]
                + av2*clsL[(2*64+d2)*33+tok] + av3*clsL[(3*64+d2)*33+tok];
        tC[d2*33 + tok] = c;
      }
      const float4* src = (const float4*)(ws + OFF_Z + hh*4096 + tid*16);
      int d2 = tid >> 2, e0 = (tid & 3)*16;
      #pragma unroll
      for (int k = 0; k < 4; ++k) {
        float4 t4 = src[k];
        *(float4*)&gL[d2*68 + e0 + k*4] = t4;
      }
    }
    __syncthreads();
    // stage3: out += Z_h @ cbar
    #pragma unroll
    for (int d2 = 0; d2 < 64; ++d2) {
      float cb = tC[d2*33 + tok];
      float4 z0 = *(float4*)&gL[d2*68 + eg*8];
      float4 z1 = *(float4*)&gL[d2*68 + eg*8 + 4];
      oacc[0] += cb*z0.x; oacc[1] += cb*z0.y; oacc[2] += cb*z0.z; oacc[3] += cb*z0.w;
      oacc[4] += cb*z1.x; oacc[5] += cb*z1.y; oacc[6] += cb*z1.z; oacc[7] += cb*z1.w;
    }
    __syncthreads();
  }
  // epilogue
  float4* dst = (float4*)(outp + (T0 + tok)*64 + eg*8);
  dst[0] = make_float4(oacc[0]+co[0], oacc[1]+co[1], oacc[2]+co[2], oacc[3]+co[3]);
  dst[1] = make_float4(oacc[4]+co[4], oacc[5]+co[5], oacc[6]+co[6], oacc[7]+co[7]);
}

extern "C" void kernel_launch(void* const* d_in, const int* in_sizes, int n_in,
                              void* d_out, int out_size, void* d_ws, size_t ws_size,
                              hipStream_t stream) {
  const float* x      = (const float*)d_in[0];
  const float* ln_g   = (const float*)d_in[1];
  const float* ln_b   = (const float*)d_in[2];
  const float* Wqkv   = (const float*)d_in[3];
  const float* bqkv   = (const float*)d_in[4];
  const float* cls_tok= (const float*)d_in[5];
  const float* Wwqkv  = (const float*)d_in[6];
  const float* bwqkv  = (const float*)d_in[7];
  const float* Wwproj = (const float*)d_in[8];
  const float* bwproj = (const float*)d_in[9];
  const float* Wraq   = (const float*)d_in[10];
  const float* Wrak   = (const float*)d_in[11];
  const float* Wrav   = (const float*)d_in[12];
  const float* Wrao   = (const float*)d_in[13];
  const float* brao   = (const float*)d_in[14];
  const float* Wout   = (const float*)d_in[15];
  const float* bout   = (const float*)d_in[16];
  float* ws = (float*)d_ws;
  float* outp = (float*)d_out;

  hipLaunchKernelGGL(k_setup1, dim3(1), dim3(256), 0, stream,
                     Wqkv, bqkv, cls_tok, Wwqkv, bwqkv, Wwproj, bwproj,
                     Wraq, Wrak, Wrav, Wrao, brao, Wout, bout, ws);
  hipLaunchKernelGGL(k_setup2, dim3(2), dim3(256), 0, stream, Wraq, Wrak, Wrav, Wwproj, ws);
  hipLaunchKernelGGL(k_setup3, dim3(2), dim3(256), 0, stream, Wwproj, Wrao, ws);
  hipLaunchKernelGGL(k_setup4, dim3(16), dim3(256), 0, stream, Wqkv, Wout, ws);
  hipLaunchKernelGGL(k_lnkv, dim3(2304), dim3(256), 0, stream, x, ln_g, ln_b, Wwqkv, bwqkv, ws);
  hipLaunchKernelGGL(k_prefix, dim3(1024), dim3(256), 0, stream, ws);
  hipLaunchKernelGGL(k_main, dim3(4608), dim3(256), 0, stream, ws, outp);
}

// Round 2
// 1392.118 us; speedup vs baseline: 3.7448x; 3.7448x over previous
//
#include <hip/hip_runtime.h>
#include <math.h>

// FourRegionAttention on MI355X (gfx950), fp32 throughout.
// B=64, n=2304 (48x48), D=64, heads=8, hd=8.
// Requires ~158 MB of d_ws.

#define SCALE_W  0.3535533905932738f   // 8^-0.5
#define SCALE_RA 0.3535533905932738f
#define LN_EPS 1e-5f

// ---- workspace layout (float offsets) ----
#define OFF_XN   0ull
#define SZ_XN    (64ull*2304*64)            // 9437184
#define OFF_KT   (OFF_XN + SZ_XN)           // k_t [b][h][n][8]
#define SZ_KT    (64ull*8*2304*8)           // 9437184
#define OFF_VT   (OFF_KT + SZ_KT)           // v_t [b][h][n][8]
#define OFF_PG   (OFF_VT + SZ_KT)           // P [b][h][49][49][9]
#define SZ_PG    (512ull*49*49*9)           // 11063808
#define OFF_ECLS (OFF_PG + SZ_PG)           // 512
#define OFF_QC   (OFF_ECLS + 512)           // 64 (scaled q_c)
#define OFF_KC   (OFF_QC + 64)              // 64
#define OFF_VC   (OFF_KC + 64)              // 64
#define OFF_CLOG (OFF_VC + 64)              // 8
#define OFF_BK   (OFF_CLOG + 8)             // 64
#define OFF_BV   (OFF_BK + 64)              // 64
#define OFF_AH   (OFF_BV + 64)              // 512 a_h = Wraq@bqkv_h
#define OFF_W1   (OFF_AH + 512)             // 64  Wraq^T@bk
#define OFF_WZ   (OFF_W1 + 64)              // 64  Wrao@bv
#define OFF_B2   (OFF_WZ + 64)              // 512 Wrak^T@a_h
#define OFF_V2   (OFF_B2 + 512)             // 512 v2_h
#define OFF_UH   (OFF_V2 + 512)             // 512 u_h
#define OFF_CH   (OFF_UH + 512)             // 8   c_h
#define OFF_C1   (OFF_CH + 8)               // 64  const output bias
#define OFF_KQ   (OFF_C1 + 64)              // 4096 Wraq^T@Wrak
#define OFF_WVE  (OFF_KQ + 4096)            // 4096 Wrav@Wwproj
#define OFF_KQP  (OFF_WVE + 4096)           // 4096 KQ@Wwproj
#define OFF_RW   (OFF_KQP + 4096)           // 4096 Wrao@WVE
#define OFF_G    (OFF_RW + 4096)            // 8*4096 G[h][d][e]
#define OFF_Z    (OFF_G + 32768)            // 8*4096 Zt[h][d][e] = Z_h[e][d]

// ---------------- setup kernels ----------------
__global__ void k_setup1(const float* __restrict__ Wqkv, const float* __restrict__ bqkv,
                         const float* __restrict__ cls_tok, const float* __restrict__ Wwqkv,
                         const float* __restrict__ bwqkv, const float* __restrict__ Wwproj,
                         const float* __restrict__ bwproj, const float* __restrict__ Wraq,
                         const float* __restrict__ Wrak, const float* __restrict__ Wrav,
                         const float* __restrict__ Wrao, const float* __restrict__ brao,
                         const float* __restrict__ Wout, const float* __restrict__ bout,
                         float* __restrict__ ws) {
  int tid = threadIdx.x;
  // phase1: cls_qkv (192), bk(64), bv(64), a_h(512)
  for (int idx = tid; idx < 832; idx += 256) {
    if (idx < 192) {
      float s = bwqkv[idx];
      for (int d = 0; d < 64; ++d) s += cls_tok[d] * Wwqkv[idx*64 + d];
      if (idx < 64) ws[OFF_QC + idx] = s * SCALE_W;
      else if (idx < 128) ws[OFF_KC + idx - 64] = s;
      else ws[OFF_VC + idx - 128] = s;
    } else if (idx < 256) {
      int e = idx - 192; float s = 0.f;
      for (int d = 0; d < 64; ++d) s += Wrak[e*64+d] * bwproj[d];
      ws[OFF_BK + e] = s;
    } else if (idx < 320) {
      int e = idx - 256; float s = 0.f;
      for (int d = 0; d < 64; ++d) s += Wrav[e*64+d] * bwproj[d];
      ws[OFF_BV + e] = s;
    } else {
      int t2 = idx - 320; int hh = t2 >> 6, e = t2 & 63; float s = 0.f;
      for (int d = 0; d < 64; ++d) s += Wraq[e*64+d] * bqkv[hh*64+d];
      ws[OFF_AH + t2] = s;
    }
  }
  __syncthreads();
  // phase2: cls_logit(8), w1(64), wz(64), b2(512), ch(8)
  for (int idx = tid; idx < 656; idx += 256) {
    if (idx < 8) {
      float s = 0.f;
      for (int u = 0; u < 8; ++u) s += ws[OFF_QC + idx*8+u] * ws[OFF_KC + idx*8+u];
      ws[OFF_CLOG + idx] = s;
    } else if (idx < 72) {
      int e = idx - 8; float s = 0.f;
      for (int d = 0; d < 64; ++d) s += Wraq[d*64+e] * ws[OFF_BK + d];
      ws[OFF_W1 + e] = s;
    } else if (idx < 136) {
      int e = idx - 72; float s = 0.f;
      for (int d = 0; d < 64; ++d) s += Wrao[e*64+d] * ws[OFF_BV + d];
      ws[OFF_WZ + e] = s;
    } else if (idx < 648) {
      int t2 = idx - 136; int hh = t2 >> 6, e = t2 & 63; float s = 0.f;
      for (int d = 0; d < 64; ++d) s += Wrak[d*64+e] * ws[OFF_AH + hh*64+d];
      ws[OFF_B2 + t2] = s;
    } else {
      int hh = idx - 648; float s = 0.f;
      for (int e = 0; e < 64; ++e) s += ws[OFF_AH + hh*64+e] * ws[OFF_BK + e];
      ws[OFF_CH + hh] = s;
    }
  }
  __syncthreads();
  // phase3: v2(512), uh(512), const1(64)
  for (int idx = tid; idx < 1088; idx += 256) {
    if (idx < 512) {
      int hh = idx >> 6, e = idx & 63; float s = 0.f;
      for (int d = 0; d < 64; ++d) s += Wwproj[d*64+e] * ws[OFF_B2 + hh*64+d];
      ws[OFF_V2 + idx] = s;
    } else if (idx < 1024) {
      int t2 = idx - 512; int hh = t2 >> 6, e = t2 & 63; float s = 0.f;
      for (int d = 0; d < 64; ++d) s += Wqkv[(hh*64+d)*64 + e] * ws[OFF_W1 + d];
      ws[OFF_UH + t2] = s;
    } else {
      int e = idx - 1024; float s = bout[e];
      for (int f = 0; f < 512; ++f)
        s += Wout[e*512+f] * (brao[f & 63] + ws[OFF_WZ + (f & 63)]);
      ws[OFF_C1 + e] = s;
    }
  }
}

__global__ void k_setup2(const float* __restrict__ Wraq, const float* __restrict__ Wrak,
                         const float* __restrict__ Wrav, const float* __restrict__ Wwproj,
                         float* __restrict__ ws) {
  int tid = threadIdx.x; int which = blockIdx.x;
  for (int t = tid; t < 4096; t += 256) {
    int i2 = t >> 6, j2 = t & 63; float s = 0.f;
    if (which == 0) { // KQ[d][e] = sum_f Wraq[f][d]*Wrak[f][e]
      for (int f = 0; f < 64; ++f) s += Wraq[f*64+i2] * Wrak[f*64+j2];
      ws[OFF_KQ + t] = s;
    } else {          // WVE[e][d] = sum_f Wrav[e][f]*Wwproj[f][d]
      for (int f = 0; f < 64; ++f) s += Wrav[i2*64+f] * Wwproj[f*64+j2];
      ws[OFF_WVE + t] = s;
    }
  }
}

__global__ void k_setup3(const float* __restrict__ Wwproj, const float* __restrict__ Wrao,
                         float* __restrict__ ws) {
  int tid = threadIdx.x; int which = blockIdx.x;
  for (int t = tid; t < 4096; t += 256) {
    int i2 = t >> 6, j2 = t & 63; float s = 0.f;
    if (which == 0) { // KQP = KQ @ Wwproj
      for (int f = 0; f < 64; ++f) s += ws[OFF_KQ + i2*64 + f] * Wwproj[f*64 + j2];
      ws[OFF_KQP + t] = s;
    } else {          // RW = Wrao @ WVE
      for (int f = 0; f < 64; ++f) s += Wrao[i2*64 + f] * ws[OFF_WVE + f*64 + j2];
      ws[OFF_RW + t] = s;
    }
  }
}

__global__ void k_setup4(const float* __restrict__ Wqkv, const float* __restrict__ Wout,
                         float* __restrict__ ws) {
  int tid = threadIdx.x; int blk = blockIdx.x;
  if (blk < 8) {       // G[h][d][e] = sum_f Wqkv[(h*64+f)][d] * KQP[f][e]
    int hh = blk;
    for (int t = tid; t < 4096; t += 256) {
      int d2 = t >> 6, e2 = t & 63; float s = 0.f;
      for (int f = 0; f < 64; ++f) s += Wqkv[(hh*64+f)*64 + d2] * ws[OFF_KQP + f*64 + e2];
      ws[OFF_G + hh*4096 + t] = s;
    }
  } else {             // Zt[h][d][e] = Z_h[e][d] = sum_f Wout[e][h*64+f] * RW[f][d]
    int hh = blk - 8;
    for (int t = tid; t < 4096; t += 256) {
      int d2 = t >> 6, e2 = t & 63; float s = 0.f;
      for (int f = 0; f < 64; ++f) s += Wout[e2*512 + hh*64 + f] * ws[OFF_RW + f*64 + d2];
      ws[OFF_Z + hh*4096 + t] = s;
    }
  }
}

// ---------------- LayerNorm + k/v GEMM ----------------
// grid 2304 blocks x 256 threads, 64 tokens/block
__global__ __launch_bounds__(256) void k_lnkv(const float* __restrict__ x,
      const float* __restrict__ ln_g, const float* __restrict__ ln_b,
      const float* __restrict__ Wwqkv, const float* __restrict__ bwqkv,
      float* __restrict__ ws) {
  __shared__ float sm[4352 + 8448 + 128];
  float* xnT = sm;                // [d][68] transposed xn tile
  float* xt  = sm + 4352;         // [tok][65]   (aliased by wkv later)
  float* wkv = sm + 4352;         // [d][132]
  float* muL = sm + 4352 + 8448;  // [64]
  float* rsL = muL + 64;          // [64]

  int tid = threadIdx.x;
  long T0 = (long)blockIdx.x * 64;
  int tok = tid >> 2, seg = tid & 3;

  // load x tile
  const float4* x4 = (const float4*)(x + (T0 + tok)*64 + seg*16);
  float4 va = x4[0], vb = x4[1], vc4 = x4[2], vd = x4[3];
  {
    float* xp = xt + tok*65 + seg*16;
    xp[0]=va.x; xp[1]=va.y; xp[2]=va.z; xp[3]=va.w;
    xp[4]=vb.x; xp[5]=vb.y; xp[6]=vb.z; xp[7]=vb.w;
    xp[8]=vc4.x; xp[9]=vc4.y; xp[10]=vc4.z; xp[11]=vc4.w;
    xp[12]=vd.x; xp[13]=vd.y; xp[14]=vd.z; xp[15]=vd.w;
  }
  __syncthreads();
  if (tid < 64) {
    float s = 0.f;
    for (int i2 = 0; i2 < 64; ++i2) s += xt[tid*65 + i2];
    float mu = s * (1.0f/64.0f);
    float v = 0.f;
    for (int i2 = 0; i2 < 64; ++i2) { float d = xt[tid*65 + i2] - mu; v += d*d; }
    v *= (1.0f/64.0f);
    muL[tid] = mu; rsL[tid] = 1.0f / sqrtf(v + LN_EPS);
  }
  __syncthreads();
  {
    float mu = muL[tok], rs = rsL[tok];
    float xv[16];
    #pragma unroll
    for (int k = 0; k < 16; ++k) {
      int i2 = seg*16 + k;
      float v = (xt[tok*65 + i2] - mu) * rs * ln_g[i2] + ln_b[i2];
      xv[k] = v;
      xnT[i2*68 + tok] = v;
    }
    float4* xng = (float4*)(ws + OFF_XN + (T0 + tok)*64 + seg*16);
    xng[0] = make_float4(xv[0], xv[1], xv[2], xv[3]);
    xng[1] = make_float4(xv[4], xv[5], xv[6], xv[7]);
    xng[2] = make_float4(xv[8], xv[9], xv[10], xv[11]);
    xng[3] = make_float4(xv[12], xv[13], xv[14], xv[15]);
  }
  __syncthreads();  // xt dead; load weights into union region
  {
    int o = tid >> 1, dh = (tid & 1) * 32;
    #pragma unroll
    for (int k = 0; k < 32; k += 4) {
      float4 w4 = *(const float4*)(Wwqkv + (64 + o)*64 + dh + k);
      wkv[(dh+k+0)*132 + o] = w4.x;
      wkv[(dh+k+1)*132 + o] = w4.y;
      wkv[(dh+k+2)*132 + o] = w4.z;
      wkv[(dh+k+3)*132 + o] = w4.w;
    }
  }
  __syncthreads();
  // GEMM: 64 tok x 128 out
  int tokq = tid & 15, og = tid >> 4;
  float acc[4][8];
  #pragma unroll
  for (int ti = 0; ti < 4; ++ti)
    #pragma unroll
    for (int k = 0; k < 8; ++k) acc[ti][k] = 0.f;
  for (int d2 = 0; d2 < 64; ++d2) {
    float4 a4 = *(float4*)&xnT[d2*68 + tokq*4];
    float4 b0 = *(float4*)&wkv[d2*132 + og*8];
    float4 b1 = *(float4*)&wkv[d2*132 + og*8 + 4];
    float aa[4] = {a4.x, a4.y, a4.z, a4.w};
    float bbv[8] = {b0.x,b0.y,b0.z,b0.w,b1.x,b1.y,b1.z,b1.w};
    #pragma unroll
    for (int ti = 0; ti < 4; ++ti)
      #pragma unroll
      for (int k = 0; k < 8; ++k) acc[ti][k] += aa[ti]*bbv[k];
  }
  int hh2 = og & 7;
  float bsv[8];
  #pragma unroll
  for (int k = 0; k < 8; ++k) bsv[k] = bwqkv[64 + og*8 + k];
  unsigned long long dstoff = (og < 8) ? OFF_KT : OFF_VT;
  #pragma unroll
  for (int ti = 0; ti < 4; ++ti) {
    long ntok = T0 + tokq*4 + ti;
    int bb = (int)(ntok / 2304);
    int nl = (int)(ntok % 2304);
    float* dst = ws + dstoff + ((long)(bb*8 + hh2)*2304 + nl)*8;
    *(float4*)dst = make_float4(acc[ti][0]+bsv[0], acc[ti][1]+bsv[1], acc[ti][2]+bsv[2], acc[ti][3]+bsv[3]);
    *(float4*)(dst+4) = make_float4(acc[ti][4]+bsv[4], acc[ti][5]+bsv[5], acc[ti][6]+bsv[6], acc[ti][7]+bsv[7]);
  }
}

// ---------------- logits + softmax-normalizer + 2D prefix sums ----------------
// grid 1024: blk = (bh<<1)|g ; g selects channel half. 256 threads.
__global__ __launch_bounds__(256) void k_prefix(float* __restrict__ ws) {
  __shared__ float lg[2304];
  __shared__ float Pp[49*49*5];
  __shared__ float red[256];
  int tid = threadIdx.x;
  int blk = blockIdx.x;
  int g = blk & 1, bh = blk >> 1;
  int hh = bh & 7;
  const float* kt = ws + OFF_KT + (long)bh*2304*8;
  const float* vt = ws + OFF_VT + (long)bh*2304*8 + (g ? 4 : 0);
  float qc[8];
  #pragma unroll
  for (int u = 0; u < 8; ++u) qc[u] = ws[OFF_QC + hh*8 + u];
  float mloc = -1e30f;
  #pragma unroll
  for (int it = 0; it < 9; ++it) {
    int nn = tid + it*256;
    const float4* kk = (const float4*)(kt + nn*8);
    float4 k0 = kk[0], k1 = kk[1];
    float lv = qc[0]*k0.x + qc[1]*k0.y + qc[2]*k0.z + qc[3]*k0.w
             + qc[4]*k1.x + qc[5]*k1.y + qc[6]*k1.z + qc[7]*k1.w;
    lg[nn] = lv;
    mloc = fmaxf(mloc, lv);
  }
  red[tid] = mloc;
  __syncthreads();
  for (int s2 = 128; s2 > 0; s2 >>= 1) {
    if (tid < s2) red[tid] = fmaxf(red[tid], red[tid + s2]);
    __syncthreads();
  }
  float m = fmaxf(red[0], ws[OFF_CLOG + hh]);
  if (tid == 0 && g == 0) ws[OFF_ECLS + bh] = expf(ws[OFF_CLOG + hh] - m);
  #pragma unroll
  for (int it = 0; it < 9; ++it) {
    int nn = tid + it*256;
    lg[nn] = expf(lg[nn] - m);
  }
  // zero P
  for (int idx = tid; idx < 49*49*5; idx += 256) Pp[idx] = 0.f;
  __syncthreads();
  int nc = g ? 4 : 5;
  #pragma unroll
  for (int it = 0; it < 9; ++it) {
    int nn = tid + it*256;
    int i2 = nn / 48, j2 = nn % 48;
    float ev = lg[nn];
    float4 v4 = *(const float4*)(vt + nn*8);
    float* cell = &Pp[((i2+1)*49 + (j2+1))*5];
    if (g == 0) {
      cell[0] = ev; cell[1] = ev*v4.x; cell[2] = ev*v4.y; cell[3] = ev*v4.z; cell[4] = ev*v4.w;
    } else {
      cell[0] = ev*v4.x; cell[1] = ev*v4.y; cell[2] = ev*v4.z; cell[3] = ev*v4.w;
    }
  }
  __syncthreads();
  // vertical cumsum (axis i) -- matches reference axis=2-first order
  for (int idx = tid; idx < 48*nc; idx += 256) {
    int j2 = idx / nc + 1, c = idx % nc;
    for (int i2 = 2; i2 <= 48; ++i2)
      Pp[(i2*49 + j2)*5 + c] += Pp[((i2-1)*49 + j2)*5 + c];
  }
  __syncthreads();
  // horizontal cumsum (axis j)
  for (int idx = tid; idx < 48*nc; idx += 256) {
    int i2 = idx / nc + 1, c = idx % nc;
    for (int j2 = 2; j2 <= 48; ++j2)
      Pp[(i2*49 + j2)*5 + c] += Pp[(i2*49 + j2 - 1)*5 + c];
  }
  __syncthreads();
  // write out P [49][49][9]
  float* pg = ws + OFF_PG + (long)bh*21609;
  int tot = 2401 * nc;
  for (int idx = tid; idx < tot; idx += 256) {
    int cell2 = idx / nc, c = idx % nc;
    pg[cell2*9 + (g ? 5 + c : c)] = Pp[cell2*5 + c];
  }
}

// ---------------- main fused kernel ----------------
// grid 4608 blocks x 256 threads, 32 tokens/block.
// LDS = 53,248 B -> 3 blocks/CU. G/Z/u weights read from global (L1-hot, only
// 2 distinct lines per wave per load). No big register arrays -> no spills.
__global__ __launch_bounds__(256) void k_main(float* __restrict__ ws,
                                              float* __restrict__ outp) {
  __shared__ float clsL[4*64*32];   // [r][e][tok]
  __shared__ float xnL[64*32];      // [d][tok]
  __shared__ float part[4*8*32];    // [r][eg][tok]
  __shared__ float tC[64*32];       // cbar [d][tok]

  int tid = threadIdx.x;
  int tok = tid & 31, eg = tid >> 5;
  long T0 = (long)blockIdx.x * 32;
  int b = (int)(T0 / 2304);
  int n = (int)(T0 % 2304) + tok;
  int i2 = n / 48, j2 = n % 48;

  // xn tile -> LDS (transposed [d][tok])
  {
    const float4* p4 = (const float4*)(ws + OFF_XN + (T0 + tok)*64 + eg*8);
    float4 xa = p4[0], xb = p4[1];
    xnL[(eg*8+0)*32 + tok] = xa.x; xnL[(eg*8+1)*32 + tok] = xa.y;
    xnL[(eg*8+2)*32 + tok] = xa.z; xnL[(eg*8+3)*32 + tok] = xa.w;
    xnL[(eg*8+4)*32 + tok] = xb.x; xnL[(eg*8+5)*32 + tok] = xb.y;
    xnL[(eg*8+6)*32 + tok] = xb.z; xnL[(eg*8+7)*32 + tok] = xb.w;
  }

  // phase0: build cls_out tile from prefix sums; thread = (tok, head=eg)
  {
    int hh = eg;
    float ec = ws[OFF_ECLS + b*8 + hh];
    const float* P = ws + OFF_PG + ((long)(b*8 + hh))*21609;
    int p_ij  = (i2*49 + j2)*9;
    int p_ij1 = p_ij + 9;
    int p_iW  = (i2*49 + 48)*9;
    int p_1j  = ((i2+1)*49 + j2)*9;
    int p_1j1 = p_1j + 9;
    int p_1W  = ((i2+1)*49 + 48)*9;
    int p_Hj  = (48*49 + j2)*9;
    int p_Hj1 = p_Hj + 9;
    int p_HW  = (48*49 + 48)*9;
    float rden[4];
    {
      float tl = P[p_1j1];
      float tr = P[p_1W] - P[p_1j];
      float bl = P[p_Hj1] - P[p_ij1];
      float br = P[p_HW] - P[p_iW] - P[p_Hj] + P[p_ij];
      rden[0] = 1.0f/(ec + tl); rden[1] = 1.0f/(ec + tr);
      rden[2] = 1.0f/(ec + bl); rden[3] = 1.0f/(ec + br);
    }
    #pragma unroll
    for (int u = 0; u < 8; ++u) {
      int c = 1 + u;
      float tl = P[p_1j1 + c];
      float tr = P[p_1W + c] - P[p_1j + c];
      float bl = P[p_Hj1 + c] - P[p_ij1 + c];
      float br = P[p_HW + c] - P[p_iW + c] - P[p_Hj + c] + P[p_ij + c];
      float nv = ec * ws[OFF_VC + hh*8 + u];
      int e = hh*8 + u;
      clsL[(0*64 + e)*32 + tok] = (nv + tl) * rden[0];
      clsL[(1*64 + e)*32 + tok] = (nv + tr) * rden[1];
      clsL[(2*64 + e)*32 + tok] = (nv + bl) * rden[2];
      clsL[(3*64 + e)*32 + tok] = (nv + br) * rden[3];
    }
  }
  __syncthreads();

  float oacc[8];
  #pragma unroll
  for (int k = 0; k < 8; ++k) oacc[k] = 0.f;

  for (int hh = 0; hh < 8; ++hh) {
    // stage1: t_h = G_h^T xn (+v2); eg0 also computes s0 = xn.u + c
    const float* Gp = ws + OFF_G + hh*4096 + eg*8;   // row stride 64 floats
    const float* Up = ws + OFF_UH + hh*64;
    float acc[8];
    #pragma unroll
    for (int k = 0; k < 8; ++k) acc[k] = ws[OFF_V2 + hh*64 + eg*8 + k];
    float as0 = (eg == 0) ? ws[OFF_CH + hh] : 0.f;
    #pragma unroll 8
    for (int d2 = 0; d2 < 64; ++d2) {
      float xv = xnL[d2*32 + tok];
      float4 g0 = *(const float4*)(Gp + d2*64);
      float4 g1 = *(const float4*)(Gp + d2*64 + 4);
      acc[0] += xv*g0.x; acc[1] += xv*g0.y; acc[2] += xv*g0.z; acc[3] += xv*g0.w;
      acc[4] += xv*g1.x; acc[5] += xv*g1.y; acc[6] += xv*g1.z; acc[7] += xv*g1.w;
      if (eg == 0) as0 += xv * Up[d2];
    }
    // stage2: score partials (eg0 folds s0 into its partials)
    #pragma unroll
    for (int r = 0; r < 4; ++r) {
      float p = as0;
      #pragma unroll
      for (int k = 0; k < 8; ++k) p += acc[k] * clsL[(r*64 + eg*8 + k)*32 + tok];
      part[(r*8 + eg)*32 + tok] = p;
    }
    __syncthreads();
    // softmax over 4 regions (all threads compute for their tok)
    float av0, av1, av2, av3;
    {
      float sc[4];
      #pragma unroll
      for (int r = 0; r < 4; ++r) {
        float s = 0.f;
        #pragma unroll
        for (int e2 = 0; e2 < 8; ++e2) s += part[(r*8 + e2)*32 + tok];
        sc[r] = s * SCALE_RA;
      }
      float mm = fmaxf(fmaxf(sc[0], sc[1]), fmaxf(sc[2], sc[3]));
      float ex0 = expf(sc[0]-mm), ex1 = expf(sc[1]-mm), ex2 = expf(sc[2]-mm), ex3 = expf(sc[3]-mm);
      float inv = 1.0f/(ex0+ex1+ex2+ex3);
      av0 = ex0*inv; av1 = ex1*inv; av2 = ex2*inv; av3 = ex3*inv;
    }
    // cbar into tC
    #pragma unroll
    for (int k = 0; k < 8; ++k) {
      int d2 = eg*8 + k;
      float c = av0*clsL[(0*64+d2)*32+tok] + av1*clsL[(1*64+d2)*32+tok]
              + av2*clsL[(2*64+d2)*32+tok] + av3*clsL[(3*64+d2)*32+tok];
      tC[d2*32 + tok] = c;
    }
    __syncthreads();
    // stage3: out += Z_h @ cbar (Z read from global, L1-hot)
    const float* Zp = ws + OFF_Z + hh*4096 + eg*8;
    #pragma unroll 8
    for (int d2 = 0; d2 < 64; ++d2) {
      float cb = tC[d2*32 + tok];
      float4 z0 = *(const float4*)(Zp + d2*64);
      float4 z1 = *(const float4*)(Zp + d2*64 + 4);
      oacc[0] += cb*z0.x; oacc[1] += cb*z0.y; oacc[2] += cb*z0.z; oacc[3] += cb*z0.w;
      oacc[4] += cb*z1.x; oacc[5] += cb*z1.y; oacc[6] += cb*z1.z; oacc[7] += cb*z1.w;
    }
  }
  // epilogue
  float co[8];
  #pragma unroll
  for (int k = 0; k < 8; ++k) co[k] = ws[OFF_C1 + eg*8 + k];
  float4* dst = (float4*)(outp + (T0 + tok)*64 + eg*8);
  dst[0] = make_float4(oacc[0]+co[0], oacc[1]+co[1], oacc[2]+co[2], oacc[3]+co[3]);
  dst[1] = make_float4(oacc[4]+co[4], oacc[5]+co[5], oacc[6]+co[6], oacc[7]+co[7]);
}

extern "C" void kernel_launch(void* const* d_in, const int* in_sizes, int n_in,
                              void* d_out, int out_size, void* d_ws, size_t ws_size,
                              hipStream_t stream) {
  const float* x      = (const float*)d_in[0];
  const float* ln_g   = (const float*)d_in[1];
  const float* ln_b   = (const float*)d_in[2];
  const float* Wqkv   = (const float*)d_in[3];
  const float* bqkv   = (const float*)d_in[4];
  const float* cls_tok= (const float*)d_in[5];
  const float* Wwqkv  = (const float*)d_in[6];
  const float* bwqkv  = (const float*)d_in[7];
  const float* Wwproj = (const float*)d_in[8];
  const float* bwproj = (const float*)d_in[9];
  const float* Wraq   = (const float*)d_in[10];
  const float* Wrak   = (const float*)d_in[11];
  const float* Wrav   = (const float*)d_in[12];
  const float* Wrao   = (const float*)d_in[13];
  const float* brao   = (const float*)d_in[14];
  const float* Wout   = (const float*)d_in[15];
  const float* bout   = (const float*)d_in[16];
  float* ws = (float*)d_ws;
  float* outp = (float*)d_out;

  hipLaunchKernelGGL(k_setup1, dim3(1), dim3(256), 0, stream,
                     Wqkv, bqkv, cls_tok, Wwqkv, bwqkv, Wwproj, bwproj,
                     Wraq, Wrak, Wrav, Wrao, brao, Wout, bout, ws);
  hipLaunchKernelGGL(k_setup2, dim3(2), dim3(256), 0, stream, Wraq, Wrak, Wrav, Wwproj, ws);
  hipLaunchKernelGGL(k_setup3, dim3(2), dim3(256), 0, stream, Wwproj, Wrao, ws);
  hipLaunchKernelGGL(k_setup4, dim3(16), dim3(256), 0, stream, Wqkv, Wout, ws);
  hipLaunchKernelGGL(k_lnkv, dim3(2304), dim3(256), 0, stream, x, ln_g, ln_b, Wwqkv, bwqkv, ws);
  hipLaunchKernelGGL(k_prefix, dim3(1024), dim3(256), 0, stream, ws);
  hipLaunchKernelGGL(k_main, dim3(4608), dim3(256), 0, stream, ws, outp);
}